// Round 4
// baseline (337.801 us; speedup 1.0000x reference)
//
#include <hip/hip_runtime.h>

// ---------------------------------------------------------------------------
// MoE block: x[2,2048,1024] fp32, 8 experts, top-2 routing, f=2048, LN output.
// v4: BK=64 GEMM K-loop (halves barrier count, 32KB LDS keeps occupancy),
//     LDS-free register 4x4 micro-transpose for weights (was 62us w/ 3.1M
//     bank-conflict cycles + scalar ds_read_u16s). Routing kernels untouched.
// ---------------------------------------------------------------------------

typedef unsigned short ushort_t;
typedef short short8 __attribute__((ext_vector_type(8)));
typedef float f32x4 __attribute__((ext_vector_type(4)));

#define T_TOKENS 4096
#define DMODEL 1024
#define FFN 2048
#define NEXP 8
#define MAXSLOTS 9216
#define GATE_BLOCKS 256
#define TOK_PER_BLK 16

__device__ __forceinline__ ushort_t f2bf(float f) {
    unsigned u = __float_as_uint(f);
    return (ushort_t)((u + 0x7fffu + ((u >> 16) & 1u)) >> 16);
}
__device__ __forceinline__ float bflo(unsigned packed) {
    return __uint_as_float(packed << 16);
}
__device__ __forceinline__ float bfhi(unsigned packed) {
    return __uint_as_float(packed & 0xffff0000u);
}

__device__ __forceinline__ void gload_lds16(const void* g, void* l) {
    __builtin_amdgcn_global_load_lds(
        (const __attribute__((address_space(1))) unsigned int*)g,
        (__attribute__((address_space(3))) unsigned int*)l,
        16, 0, 0);
}

// ---------------------------------------------------------------------------
// 1) gating: fp32 logits (Wg register-cached), top-2, softmax weights.
//    (unchanged from v3)
__global__ __launch_bounds__(256) void gate_kernel(
    const float* __restrict__ x, const float* __restrict__ Wg,
    const float* __restrict__ bg,
    int* __restrict__ top_idx, float* __restrict__ top_w,
    int* __restrict__ blk_hist)
{
    __shared__ int hist[NEXP];
    const int tid = threadIdx.x, lane = tid & 63, w = tid >> 6;
    if (tid < NEXP) hist[tid] = 0;
    __syncthreads();

    float wreg[16][8];
    #pragma unroll
    for (int i = 0; i < 16; i++) {
        const float4* wp = (const float4*)&Wg[(i * 64 + lane) * 8];
        float4 a = wp[0], b = wp[1];
        wreg[i][0] = a.x; wreg[i][1] = a.y; wreg[i][2] = a.z; wreg[i][3] = a.w;
        wreg[i][4] = b.x; wreg[i][5] = b.y; wreg[i][6] = b.z; wreg[i][7] = b.w;
    }
    float bgv[8];
    #pragma unroll
    for (int e = 0; e < 8; e++) bgv[e] = bg[e];

    const int t0 = blockIdx.x * TOK_PER_BLK + w * 4;
    #pragma unroll 1
    for (int it = 0; it < 4; it++) {
        int t = t0 + it;
        const float* xr = x + (size_t)t * DMODEL;
        float acc[8] = {0.f,0.f,0.f,0.f,0.f,0.f,0.f,0.f};
        #pragma unroll
        for (int i = 0; i < 16; i++) {
            float xv = xr[i * 64 + lane];
            #pragma unroll
            for (int e = 0; e < 8; e++) acc[e] += xv * wreg[i][e];
        }
        #pragma unroll
        for (int off = 32; off > 0; off >>= 1) {
            #pragma unroll
            for (int e = 0; e < 8; e++) acc[e] += __shfl_down(acc[e], off);
        }
        if (lane == 0) {
            float l[8];
            #pragma unroll
            for (int e = 0; e < 8; e++) l[e] = acc[e] + bgv[e];
            int i0 = 0; float v0 = l[0];
            #pragma unroll
            for (int e = 1; e < 8; e++) if (l[e] > v0) { v0 = l[e]; i0 = e; }
            int i1 = -1; float v1 = -1e30f;
            #pragma unroll
            for (int e = 0; e < 8; e++) if (e != i0 && l[e] > v1) { v1 = l[e]; i1 = e; }
            float eg = expf(v1 - v0);
            float den = 1.f + eg;
            int p0 = atomicAdd(&hist[i0], 1);
            int p1 = atomicAdd(&hist[i1], 1);
            top_idx[2 * t]     = i0 | (p0 << 4);
            top_idx[2 * t + 1] = i1 | (p1 << 4);
            top_w[2 * t]     = 1.f / den;
            top_w[2 * t + 1] = eg / den;
        }
    }
    __syncthreads();
    if (tid < NEXP) blk_hist[blockIdx.x * NEXP + tid] = hist[tid];
}

// ---------------------------------------------------------------------------
// 2) scan (unchanged)
__global__ __launch_bounds__(512) void scan_kernel(
    const int* __restrict__ blk_hist, int* __restrict__ blk_base,
    int* __restrict__ offs)
{
    __shared__ int cnt[NEXP];
    const int tid = threadIdx.x, lane = tid & 63, e = tid >> 6;
    int carry = 0;
    #pragma unroll
    for (int r = 0; r < GATE_BLOCKS / 64; r++) {
        int b = r * 64 + lane;
        int orig = blk_hist[b * NEXP + e];
        int v = orig;
        #pragma unroll
        for (int off = 1; off < 64; off <<= 1) {
            int u = __shfl_up(v, off);
            if (lane >= off) v += u;
        }
        blk_base[b * NEXP + e] = carry + v - orig;
        carry += __shfl(v, 63);
    }
    if (lane == 0) cnt[e] = carry;
    __syncthreads();
    if (tid == 0) {
        int cum = 0;
        for (int ee = 0; ee < NEXP; ee++) {
            offs[ee] = cum;
            cum += (cnt[ee] + 127) & ~127;
        }
        offs[NEXP] = cum;
    }
}

// ---------------------------------------------------------------------------
// 3) fused scatter + gather (unchanged)
__global__ __launch_bounds__(256) void scatter_gather_kernel(
    const float* __restrict__ x, const int* __restrict__ top_idx,
    const int* __restrict__ offs, const int* __restrict__ blk_base,
    int* __restrict__ slot_of, ushort_t* __restrict__ Xg)
{
    const int t = blockIdx.x, tid = threadIdx.x;
    __shared__ int slots[2];
    if (tid < 2) {
        int v = top_idx[2 * t + tid];
        int e = v & 15, pos = v >> 4;
        int gb = t / TOK_PER_BLK;
        int slot = offs[e] + blk_base[gb * NEXP + e] + pos;
        slot_of[2 * t + tid] = slot;
        slots[tid] = slot;
    }
    __syncthreads();
    float4 xv = ((const float4*)(x + (size_t)t * DMODEL))[tid];
    uint2 pk;
    pk.x = f2bf(xv.x) | ((unsigned)f2bf(xv.y) << 16);
    pk.y = f2bf(xv.z) | ((unsigned)f2bf(xv.w) << 16);
    ((uint2*)(Xg + (size_t)slots[0] * DMODEL))[tid] = pk;
    ((uint2*)(Xg + (size_t)slots[1] * DMODEL))[tid] = pk;
}

// ---------------------------------------------------------------------------
// 4) fused transpose+convert, LDS-free register 4x4 micro-transpose.
//    [E][Rs][Cs] f32 -> [E][Cs][Rs] bf16. Loads: 16 lanes x 4 rows x 16B
//    (full 64B lines); stores: 16 lanes x 8B = 128B contiguous per dst row.
__global__ __launch_bounds__(256) void transpose_kernel(
    const float* __restrict__ W1, const float* __restrict__ W2,
    ushort_t* __restrict__ W1T, ushort_t* __restrict__ W2T)
{
    int b = blockIdx.x;
    const float* s; ushort_t* d; int Rs, Cs, rt, ct;
    if (b < 4096) {                 // W1: Rs=1024, Cs=2048 -> 16 x 32 tiles
        int e = b >> 9, t = b & 511;
        rt = t >> 5; ct = t & 31;
        s = W1 + (size_t)e * DMODEL * FFN;
        d = W1T + (size_t)e * DMODEL * FFN;
        Rs = DMODEL; Cs = FFN;
    } else {                        // W2: Rs=2048, Cs=1024 -> 32 x 16 tiles
        b -= 4096;
        int e = b >> 9, t = b & 511;
        rt = t >> 4; ct = t & 15;
        s = W2 + (size_t)e * DMODEL * FFN;
        d = W2T + (size_t)e * DMODEL * FFN;
        Rs = FFN; Cs = DMODEL;
    }
    const int r0 = rt * 64, c0 = ct * 64;
    const int ty = threadIdx.x & 15, tx = threadIdx.x >> 4;

    float v[4][4];
    #pragma unroll
    for (int i = 0; i < 4; i++) {
        float4 ld = *(const float4*)&s[(size_t)(r0 + ty * 4 + i) * Cs + c0 + tx * 4];
        v[i][0] = ld.x; v[i][1] = ld.y; v[i][2] = ld.z; v[i][3] = ld.w;
    }
    #pragma unroll
    for (int j = 0; j < 4; j++) {
        uint2 pk;
        pk.x = f2bf(v[0][j]) | ((unsigned)f2bf(v[1][j]) << 16);
        pk.y = f2bf(v[2][j]) | ((unsigned)f2bf(v[3][j]) << 16);
        *(uint2*)&d[(size_t)(c0 + tx * 4 + j) * Rs + r0 + ty * 4] = pk;
    }
}

// ---------------------------------------------------------------------------
// 5) grouped expert GEMM, BK=64: C = A[M,K] * Bt[N,K]^T + bias, bf16 out.
//    gridDim.x = 8 = expert -> XCD pinning. 32KB LDS (2 x 128rows x 64k).
//    Swizzle: LDS slot s (16B chunks, 8/row) of row r holds global chunk s^(r&7).
template <int K, int N, bool RELU>
__global__ __launch_bounds__(256) void expert_gemm(
    const ushort_t* __restrict__ A,
    const ushort_t* __restrict__ Bt,
    const float* __restrict__ bias,
    ushort_t* __restrict__ Cout,
    const int* __restrict__ offs)
{
    const int e  = blockIdx.x;
    const int nt = blockIdx.y;
    const int mt = blockIdx.z;
    const int off_e = offs[e];
    const int Mpad  = offs[e + 1] - off_e;
    if (mt * 128 >= Mpad) return;

    __shared__ __align__(16) ushort_t As[128 * 64];
    __shared__ __align__(16) ushort_t Bs[128 * 64];

    const int tid  = threadIdx.x;
    const int lane = tid & 63;
    const int w    = tid >> 6;
    const int quad = lane >> 4;
    const int r16  = lane & 15;
    const int srow = lane >> 3;                       // staging row 0..7 within 8-row group
    const int schunk = (lane & 7) ^ srow;             // swizzled source 16B chunk

    const size_t arow0 = (size_t)(off_e + mt * 128);
    // wave w stages rows [w*32, w*32+32) of both A and B tiles, 8 rows/inst
    const ushort_t* aBase = A + (arow0 + w * 32 + srow) * (size_t)K + schunk * 8;
    const ushort_t* Bte = Bt + (size_t)e * N * K;
    const ushort_t* bBase = Bte + ((size_t)(nt * 128 + w * 32 + srow)) * K + schunk * 8;
    ushort_t* aLds = &As[(w * 32) * 64];
    ushort_t* bLds = &Bs[(w * 32) * 64];

    const int wm = (w >> 1) * 64;
    const int wn = (w & 1) * 64;
    const int rk = r16 & 7;                            // read-side swizzle key

    f32x4 acc[4][4];
    #pragma unroll
    for (int i = 0; i < 4; i++)
        #pragma unroll
        for (int j = 0; j < 4; j++)
            acc[i][j] = (f32x4){0.f, 0.f, 0.f, 0.f};

    for (int k0 = 0; k0 < K; k0 += 64) {
        #pragma unroll
        for (int i = 0; i < 4; i++)
            gload_lds16(aBase + k0 + (size_t)i * 8 * K, aLds + i * 512);
        #pragma unroll
        for (int i = 0; i < 4; i++)
            gload_lds16(bBase + k0 + (size_t)i * 8 * K, bLds + i * 512);
        __syncthreads();
        #pragma unroll
        for (int kc = 0; kc < 2; kc++) {
            short8 af[4], bfr[4];
            #pragma unroll
            for (int i = 0; i < 4; i++)
                af[i] = *(const short8*)&As[(wm + i * 16 + r16) * 64
                                            + (((kc * 4 + quad) ^ rk)) * 8];
            #pragma unroll
            for (int j = 0; j < 4; j++)
                bfr[j] = *(const short8*)&Bs[(wn + j * 16 + r16) * 64
                                             + (((kc * 4 + quad) ^ rk)) * 8];
            #pragma unroll
            for (int i = 0; i < 4; i++)
                #pragma unroll
                for (int j = 0; j < 4; j++)
                    acc[i][j] = __builtin_amdgcn_mfma_f32_16x16x32_bf16(
                        af[i], bfr[j], acc[i][j], 0, 0, 0);
        }
        __syncthreads();
    }

    const float* be = bias + (size_t)e * N;
    #pragma unroll
    for (int i = 0; i < 4; i++) {
        #pragma unroll
        for (int j = 0; j < 4; j++) {
            int n = nt * 128 + wn + j * 16 + r16;
            float bv = be[n];
            #pragma unroll
            for (int r = 0; r < 4; r++) {
                int m = mt * 128 + wm + i * 16 + quad * 4 + r;
                float v = acc[i][j][r] + bv;
                if (RELU) v = v > 0.f ? v : 0.f;
                Cout[(size_t)(off_e + m) * N + n] = f2bf(v);
            }
        }
    }
}

// ---------------------------------------------------------------------------
// 6) fused mix + residual + LayerNorm (unchanged)
__global__ __launch_bounds__(256) void ln_kernel(
    const float* __restrict__ x, const ushort_t* __restrict__ O,
    const int* __restrict__ slot_of, const float* __restrict__ top_w,
    const float* __restrict__ gamma, const float* __restrict__ beta,
    float* __restrict__ out)
{
    int t = blockIdx.x, tid = threadIdx.x;
    int s0 = slot_of[2 * t], s1 = slot_of[2 * t + 1];
    float w0 = top_w[2 * t], w1 = top_w[2 * t + 1];
    float4 xv = ((const float4*)(x + (size_t)t * DMODEL))[tid];
    uint2 a = ((const uint2*)(O + (size_t)s0 * DMODEL))[tid];
    uint2 b = ((const uint2*)(O + (size_t)s1 * DMODEL))[tid];

    float y[4];
    y[0] = xv.x + w0 * bflo(a.x) + w1 * bflo(b.x);
    y[1] = xv.y + w0 * bfhi(a.x) + w1 * bfhi(b.x);
    y[2] = xv.z + w0 * bflo(a.y) + w1 * bflo(b.y);
    y[3] = xv.w + w0 * bfhi(a.y) + w1 * bfhi(b.y);

    float s = y[0] + y[1] + y[2] + y[3];
    float sq = y[0]*y[0] + y[1]*y[1] + y[2]*y[2] + y[3]*y[3];
    __shared__ float red[2][4];
    #pragma unroll
    for (int off = 32; off > 0; off >>= 1) {
        s += __shfl_down(s, off);
        sq += __shfl_down(sq, off);
    }
    int lane = tid & 63, wv = tid >> 6;
    if (lane == 0) { red[0][wv] = s; red[1][wv] = sq; }
    __syncthreads();
    if (tid == 0) {
        float S = red[0][0] + red[0][1] + red[0][2] + red[0][3];
        float SQ = red[1][0] + red[1][1] + red[1][2] + red[1][3];
        float mu = S * (1.f / DMODEL);
        float var = SQ * (1.f / DMODEL) - mu * mu;
        red[0][0] = mu;
        red[1][0] = rsqrtf(var + 1e-5f);
    }
    __syncthreads();
    float mu = red[0][0], inv = red[1][0];
    float4 gv = ((const float4*)gamma)[tid];
    float4 bv = ((const float4*)beta)[tid];
    float4 ov;
    ov.x = gv.x * (y[0] - mu) * inv + bv.x;
    ov.y = gv.y * (y[1] - mu) * inv + bv.y;
    ov.z = gv.z * (y[2] - mu) * inv + bv.z;
    ov.w = gv.w * (y[3] - mu) * inv + bv.w;
    ((float4*)(out + (size_t)t * DMODEL))[tid] = ov;
}

// ---------------------------------------------------------------------------
extern "C" void kernel_launch(void* const* d_in, const int* in_sizes, int n_in,
                              void* d_out, int out_size, void* d_ws, size_t ws_size,
                              hipStream_t stream)
{
    const float* x     = (const float*)d_in[0];
    const float* Wg    = (const float*)d_in[1];
    const float* bg    = (const float*)d_in[2];
    const float* W1    = (const float*)d_in[3];
    const float* b1    = (const float*)d_in[4];
    const float* W2    = (const float*)d_in[5];
    const float* b2    = (const float*)d_in[6];
    const float* gamma = (const float*)d_in[7];
    const float* beta  = (const float*)d_in[8];
    float* out = (float*)d_out;

    char* ws = (char*)d_ws;
    size_t o = 0;
    auto alloc = [&](size_t bytes) {
        size_t r = o;
        o = (o + bytes + 255) & ~(size_t)255;
        return r;
    };
    size_t o_offs    = alloc((NEXP + 1) * 4);
    size_t o_topidx  = alloc((size_t)T_TOKENS * 2 * 4);
    size_t o_topw    = alloc((size_t)T_TOKENS * 2 * 4);
    size_t o_slotof  = alloc((size_t)T_TOKENS * 2 * 4);
    size_t o_bhist   = alloc((size_t)GATE_BLOCKS * NEXP * 4);
    size_t o_bbase   = alloc((size_t)GATE_BLOCKS * NEXP * 4);
    size_t o_w1t     = alloc((size_t)NEXP * DMODEL * FFN * 2);
    size_t o_w2t     = alloc((size_t)NEXP * DMODEL * FFN * 2);
    size_t o_xg      = alloc((size_t)MAXSLOTS * DMODEL * 2);
    size_t o_h       = alloc((size_t)MAXSLOTS * FFN * 2);
    size_t o_obuf    = alloc((size_t)MAXSLOTS * DMODEL * 2);
    (void)ws_size; (void)in_sizes; (void)n_in; (void)out_size;

    int*      offs     = (int*)(ws + o_offs);
    int*      top_idx  = (int*)(ws + o_topidx);
    float*    top_w    = (float*)(ws + o_topw);
    int*      slot_of  = (int*)(ws + o_slotof);
    int*      blk_hist = (int*)(ws + o_bhist);
    int*      blk_base = (int*)(ws + o_bbase);
    ushort_t* W1T      = (ushort_t*)(ws + o_w1t);
    ushort_t* W2T      = (ushort_t*)(ws + o_w2t);
    ushort_t* Xg       = (ushort_t*)(ws + o_xg);
    ushort_t* H        = (ushort_t*)(ws + o_h);
    ushort_t* Obuf     = (ushort_t*)(ws + o_obuf);

    gate_kernel<<<GATE_BLOCKS, 256, 0, stream>>>(x, Wg, bg, top_idx, top_w, blk_hist);
    transpose_kernel<<<8192, 256, 0, stream>>>(W1, W2, W1T, W2T);
    scan_kernel<<<1, 512, 0, stream>>>(blk_hist, blk_base, offs);
    scatter_gather_kernel<<<T_TOKENS, 256, 0, stream>>>(x, top_idx, offs, blk_base, slot_of, Xg);
    expert_gemm<DMODEL, FFN, true>
        <<<dim3(NEXP, FFN / 128, 32), 256, 0, stream>>>(Xg, W1T, b1, H, offs);
    expert_gemm<FFN, DMODEL, false>
        <<<dim3(NEXP, DMODEL / 128, 32), 256, 0, stream>>>(H, W2T, b2, Obuf, offs);
    ln_kernel<<<T_TOKENS, 256, 0, stream>>>(x, Obuf, slot_of, top_w, gamma, beta, out);
}

// Round 5
// 315.376 us; speedup vs baseline: 1.0711x; 1.0711x over previous
//
#include <hip/hip_runtime.h>

// ---------------------------------------------------------------------------
// MoE block: x[2,2048,1024] fp32, 8 experts, top-2 routing, f=2048, LN output.
// v5: GEMM reverted to v3's proven BK=32 structure (BK=64 regressed 24%:
//     occupancy 19->12.4%, m132's lesson). Kept v4 register transpose.
//     GEMM grid z trimmed 32->12 (routing counts are 1024+-30; 16 sigma).
// ---------------------------------------------------------------------------

typedef unsigned short ushort_t;
typedef short short8 __attribute__((ext_vector_type(8)));
typedef float f32x4 __attribute__((ext_vector_type(4)));

#define T_TOKENS 4096
#define DMODEL 1024
#define FFN 2048
#define NEXP 8
#define MAXSLOTS 9216
#define GATE_BLOCKS 256
#define TOK_PER_BLK 16
#define MAX_MT 12          // max 1536 rows/expert

__device__ __forceinline__ ushort_t f2bf(float f) {
    unsigned u = __float_as_uint(f);
    return (ushort_t)((u + 0x7fffu + ((u >> 16) & 1u)) >> 16);
}
__device__ __forceinline__ float bflo(unsigned packed) {
    return __uint_as_float(packed << 16);
}
__device__ __forceinline__ float bfhi(unsigned packed) {
    return __uint_as_float(packed & 0xffff0000u);
}

__device__ __forceinline__ void gload_lds16(const void* g, void* l) {
    __builtin_amdgcn_global_load_lds(
        (const __attribute__((address_space(1))) unsigned int*)g,
        (__attribute__((address_space(3))) unsigned int*)l,
        16, 0, 0);
}

// ---------------------------------------------------------------------------
// 1) gating: fp32 logits (Wg register-cached), top-2, softmax weights.
__global__ __launch_bounds__(256) void gate_kernel(
    const float* __restrict__ x, const float* __restrict__ Wg,
    const float* __restrict__ bg,
    int* __restrict__ top_idx, float* __restrict__ top_w,
    int* __restrict__ blk_hist)
{
    __shared__ int hist[NEXP];
    const int tid = threadIdx.x, lane = tid & 63, w = tid >> 6;
    if (tid < NEXP) hist[tid] = 0;
    __syncthreads();

    float wreg[16][8];
    #pragma unroll
    for (int i = 0; i < 16; i++) {
        const float4* wp = (const float4*)&Wg[(i * 64 + lane) * 8];
        float4 a = wp[0], b = wp[1];
        wreg[i][0] = a.x; wreg[i][1] = a.y; wreg[i][2] = a.z; wreg[i][3] = a.w;
        wreg[i][4] = b.x; wreg[i][5] = b.y; wreg[i][6] = b.z; wreg[i][7] = b.w;
    }
    float bgv[8];
    #pragma unroll
    for (int e = 0; e < 8; e++) bgv[e] = bg[e];

    const int t0 = blockIdx.x * TOK_PER_BLK + w * 4;
    #pragma unroll 1
    for (int it = 0; it < 4; it++) {
        int t = t0 + it;
        const float* xr = x + (size_t)t * DMODEL;
        float acc[8] = {0.f,0.f,0.f,0.f,0.f,0.f,0.f,0.f};
        #pragma unroll
        for (int i = 0; i < 16; i++) {
            float xv = xr[i * 64 + lane];
            #pragma unroll
            for (int e = 0; e < 8; e++) acc[e] += xv * wreg[i][e];
        }
        #pragma unroll
        for (int off = 32; off > 0; off >>= 1) {
            #pragma unroll
            for (int e = 0; e < 8; e++) acc[e] += __shfl_down(acc[e], off);
        }
        if (lane == 0) {
            float l[8];
            #pragma unroll
            for (int e = 0; e < 8; e++) l[e] = acc[e] + bgv[e];
            int i0 = 0; float v0 = l[0];
            #pragma unroll
            for (int e = 1; e < 8; e++) if (l[e] > v0) { v0 = l[e]; i0 = e; }
            int i1 = -1; float v1 = -1e30f;
            #pragma unroll
            for (int e = 0; e < 8; e++) if (e != i0 && l[e] > v1) { v1 = l[e]; i1 = e; }
            float eg = expf(v1 - v0);
            float den = 1.f + eg;
            int p0 = atomicAdd(&hist[i0], 1);
            int p1 = atomicAdd(&hist[i1], 1);
            top_idx[2 * t]     = i0 | (p0 << 4);
            top_idx[2 * t + 1] = i1 | (p1 << 4);
            top_w[2 * t]     = 1.f / den;
            top_w[2 * t + 1] = eg / den;
        }
    }
    __syncthreads();
    if (tid < NEXP) blk_hist[blockIdx.x * NEXP + tid] = hist[tid];
}

// ---------------------------------------------------------------------------
// 2) scan: per-expert exclusive prefix over block histograms + padded offsets.
__global__ __launch_bounds__(512) void scan_kernel(
    const int* __restrict__ blk_hist, int* __restrict__ blk_base,
    int* __restrict__ offs)
{
    __shared__ int cnt[NEXP];
    const int tid = threadIdx.x, lane = tid & 63, e = tid >> 6;
    int carry = 0;
    #pragma unroll
    for (int r = 0; r < GATE_BLOCKS / 64; r++) {
        int b = r * 64 + lane;
        int orig = blk_hist[b * NEXP + e];
        int v = orig;
        #pragma unroll
        for (int off = 1; off < 64; off <<= 1) {
            int u = __shfl_up(v, off);
            if (lane >= off) v += u;
        }
        blk_base[b * NEXP + e] = carry + v - orig;
        carry += __shfl(v, 63);
    }
    if (lane == 0) cnt[e] = carry;
    __syncthreads();
    if (tid == 0) {
        int cum = 0;
        for (int ee = 0; ee < NEXP; ee++) {
            offs[ee] = cum;
            cum += (cnt[ee] + 127) & ~127;
        }
        offs[NEXP] = cum;
    }
}

// ---------------------------------------------------------------------------
// 3) fused scatter + gather
__global__ __launch_bounds__(256) void scatter_gather_kernel(
    const float* __restrict__ x, const int* __restrict__ top_idx,
    const int* __restrict__ offs, const int* __restrict__ blk_base,
    int* __restrict__ slot_of, ushort_t* __restrict__ Xg)
{
    const int t = blockIdx.x, tid = threadIdx.x;
    __shared__ int slots[2];
    if (tid < 2) {
        int v = top_idx[2 * t + tid];
        int e = v & 15, pos = v >> 4;
        int gb = t / TOK_PER_BLK;
        int slot = offs[e] + blk_base[gb * NEXP + e] + pos;
        slot_of[2 * t + tid] = slot;
        slots[tid] = slot;
    }
    __syncthreads();
    float4 xv = ((const float4*)(x + (size_t)t * DMODEL))[tid];
    uint2 pk;
    pk.x = f2bf(xv.x) | ((unsigned)f2bf(xv.y) << 16);
    pk.y = f2bf(xv.z) | ((unsigned)f2bf(xv.w) << 16);
    ((uint2*)(Xg + (size_t)slots[0] * DMODEL))[tid] = pk;
    ((uint2*)(Xg + (size_t)slots[1] * DMODEL))[tid] = pk;
}

// ---------------------------------------------------------------------------
// 4) fused transpose+convert, LDS-free register 4x4 micro-transpose (v4).
__global__ __launch_bounds__(256) void transpose_kernel(
    const float* __restrict__ W1, const float* __restrict__ W2,
    ushort_t* __restrict__ W1T, ushort_t* __restrict__ W2T)
{
    int b = blockIdx.x;
    const float* s; ushort_t* d; int Rs, Cs, rt, ct;
    if (b < 4096) {                 // W1: Rs=1024, Cs=2048 -> 16 x 32 tiles
        int e = b >> 9, t = b & 511;
        rt = t >> 5; ct = t & 31;
        s = W1 + (size_t)e * DMODEL * FFN;
        d = W1T + (size_t)e * DMODEL * FFN;
        Rs = DMODEL; Cs = FFN;
    } else {                        // W2: Rs=2048, Cs=1024 -> 32 x 16 tiles
        b -= 4096;
        int e = b >> 9, t = b & 511;
        rt = t >> 4; ct = t & 15;
        s = W2 + (size_t)e * DMODEL * FFN;
        d = W2T + (size_t)e * DMODEL * FFN;
        Rs = FFN; Cs = DMODEL;
    }
    const int r0 = rt * 64, c0 = ct * 64;
    const int ty = threadIdx.x & 15, tx = threadIdx.x >> 4;

    float v[4][4];
    #pragma unroll
    for (int i = 0; i < 4; i++) {
        float4 ld = *(const float4*)&s[(size_t)(r0 + ty * 4 + i) * Cs + c0 + tx * 4];
        v[i][0] = ld.x; v[i][1] = ld.y; v[i][2] = ld.z; v[i][3] = ld.w;
    }
    #pragma unroll
    for (int j = 0; j < 4; j++) {
        uint2 pk;
        pk.x = f2bf(v[0][j]) | ((unsigned)f2bf(v[1][j]) << 16);
        pk.y = f2bf(v[2][j]) | ((unsigned)f2bf(v[3][j]) << 16);
        *(uint2*)&d[(size_t)(c0 + tx * 4 + j) * Rs + r0 + ty * 4] = pk;
    }
}

// ---------------------------------------------------------------------------
// 5) grouped expert GEMM (v3 proven structure, BK=32, 16KB LDS):
//    C = A[M,K] * Bt[N,K]^T + bias, bf16 out. gridDim.x = 8 = expert (XCD pin).
//    XOR-swizzled LDS chunks (0 bank conflicts measured).
template <int K, int N, bool RELU>
__global__ __launch_bounds__(256) void expert_gemm(
    const ushort_t* __restrict__ A,
    const ushort_t* __restrict__ Bt,
    const float* __restrict__ bias,
    ushort_t* __restrict__ Cout,
    const int* __restrict__ offs)
{
    const int e  = blockIdx.x;
    const int nt = blockIdx.y;
    const int mt = blockIdx.z;
    const int off_e = offs[e];
    const int Mpad  = offs[e + 1] - off_e;
    if (mt * 128 >= Mpad) return;

    __shared__ __align__(16) ushort_t As[128 * 32];
    __shared__ __align__(16) ushort_t Bs[128 * 32];

    const int tid  = threadIdx.x;
    const int lane = tid & 63;
    const int w    = tid >> 6;
    const int quad = lane >> 4;
    const int r16  = lane & 15;
    const int lrow = lane >> 2;                          // staging row 0..15
    const int lk   = (((lane & 3) ^ ((lane >> 3) & 3))) * 8;  // swizzled src k

    const size_t arow0 = (size_t)(off_e + mt * 128);
    const ushort_t* aS0 = A + (arow0 + (size_t)(2 * w + 0) * 16 + lrow) * K + lk;
    const ushort_t* aS1 = A + (arow0 + (size_t)(2 * w + 1) * 16 + lrow) * K + lk;
    const ushort_t* Bte = Bt + (size_t)e * N * K;
    const ushort_t* bS0 = Bte + ((size_t)(nt * 128 + (2 * w + 0) * 16 + lrow)) * K + lk;
    const ushort_t* bS1 = Bte + ((size_t)(nt * 128 + (2 * w + 1) * 16 + lrow)) * K + lk;
    ushort_t* aD0 = &As[(2 * w + 0) * 512];
    ushort_t* aD1 = &As[(2 * w + 1) * 512];
    ushort_t* bD0 = &Bs[(2 * w + 0) * 512];
    ushort_t* bD1 = &Bs[(2 * w + 1) * 512];

    const int wm = (w >> 1) * 64;
    const int wn = (w & 1) * 64;
    const int sw = ((r16 >> 1) & 3) ^ quad;   // swizzled read chunk

    f32x4 acc[4][4];
    #pragma unroll
    for (int i = 0; i < 4; i++)
        #pragma unroll
        for (int j = 0; j < 4; j++)
            acc[i][j] = (f32x4){0.f, 0.f, 0.f, 0.f};

    for (int k0 = 0; k0 < K; k0 += 32) {
        gload_lds16(aS0 + k0, aD0);
        gload_lds16(aS1 + k0, aD1);
        gload_lds16(bS0 + k0, bD0);
        gload_lds16(bS1 + k0, bD1);
        __syncthreads();
        short8 af[4], bfr[4];
        #pragma unroll
        for (int i = 0; i < 4; i++)
            af[i] = *(const short8*)&As[(wm + i * 16 + r16) * 32 + sw * 8];
        #pragma unroll
        for (int j = 0; j < 4; j++)
            bfr[j] = *(const short8*)&Bs[(wn + j * 16 + r16) * 32 + sw * 8];
        #pragma unroll
        for (int i = 0; i < 4; i++)
            #pragma unroll
            for (int j = 0; j < 4; j++)
                acc[i][j] = __builtin_amdgcn_mfma_f32_16x16x32_bf16(
                    af[i], bfr[j], acc[i][j], 0, 0, 0);
        __syncthreads();
    }

    const float* be = bias + (size_t)e * N;
    #pragma unroll
    for (int i = 0; i < 4; i++) {
        #pragma unroll
        for (int j = 0; j < 4; j++) {
            int n = nt * 128 + wn + j * 16 + r16;
            float bv = be[n];
            #pragma unroll
            for (int r = 0; r < 4; r++) {
                int m = mt * 128 + wm + i * 16 + quad * 4 + r;
                float v = acc[i][j][r] + bv;
                if (RELU) v = v > 0.f ? v : 0.f;
                Cout[(size_t)(off_e + m) * N + n] = f2bf(v);
            }
        }
    }
}

// ---------------------------------------------------------------------------
// 6) fused mix + residual + LayerNorm
__global__ __launch_bounds__(256) void ln_kernel(
    const float* __restrict__ x, const ushort_t* __restrict__ O,
    const int* __restrict__ slot_of, const float* __restrict__ top_w,
    const float* __restrict__ gamma, const float* __restrict__ beta,
    float* __restrict__ out)
{
    int t = blockIdx.x, tid = threadIdx.x;
    int s0 = slot_of[2 * t], s1 = slot_of[2 * t + 1];
    float w0 = top_w[2 * t], w1 = top_w[2 * t + 1];
    float4 xv = ((const float4*)(x + (size_t)t * DMODEL))[tid];
    uint2 a = ((const uint2*)(O + (size_t)s0 * DMODEL))[tid];
    uint2 b = ((const uint2*)(O + (size_t)s1 * DMODEL))[tid];

    float y[4];
    y[0] = xv.x + w0 * bflo(a.x) + w1 * bflo(b.x);
    y[1] = xv.y + w0 * bfhi(a.x) + w1 * bfhi(b.x);
    y[2] = xv.z + w0 * bflo(a.y) + w1 * bflo(b.y);
    y[3] = xv.w + w0 * bfhi(a.y) + w1 * bfhi(b.y);

    float s = y[0] + y[1] + y[2] + y[3];
    float sq = y[0]*y[0] + y[1]*y[1] + y[2]*y[2] + y[3]*y[3];
    __shared__ float red[2][4];
    #pragma unroll
    for (int off = 32; off > 0; off >>= 1) {
        s += __shfl_down(s, off);
        sq += __shfl_down(sq, off);
    }
    int lane = tid & 63, wv = tid >> 6;
    if (lane == 0) { red[0][wv] = s; red[1][wv] = sq; }
    __syncthreads();
    if (tid == 0) {
        float S = red[0][0] + red[0][1] + red[0][2] + red[0][3];
        float SQ = red[1][0] + red[1][1] + red[1][2] + red[1][3];
        float mu = S * (1.f / DMODEL);
        float var = SQ * (1.f / DMODEL) - mu * mu;
        red[0][0] = mu;
        red[1][0] = rsqrtf(var + 1e-5f);
    }
    __syncthreads();
    float mu = red[0][0], inv = red[1][0];
    float4 gv = ((const float4*)gamma)[tid];
    float4 bv = ((const float4*)beta)[tid];
    float4 ov;
    ov.x = gv.x * (y[0] - mu) * inv + bv.x;
    ov.y = gv.y * (y[1] - mu) * inv + bv.y;
    ov.z = gv.z * (y[2] - mu) * inv + bv.z;
    ov.w = gv.w * (y[3] - mu) * inv + bv.w;
    ((float4*)(out + (size_t)t * DMODEL))[tid] = ov;
}

// ---------------------------------------------------------------------------
extern "C" void kernel_launch(void* const* d_in, const int* in_sizes, int n_in,
                              void* d_out, int out_size, void* d_ws, size_t ws_size,
                              hipStream_t stream)
{
    const float* x     = (const float*)d_in[0];
    const float* Wg    = (const float*)d_in[1];
    const float* bg    = (const float*)d_in[2];
    const float* W1    = (const float*)d_in[3];
    const float* b1    = (const float*)d_in[4];
    const float* W2    = (const float*)d_in[5];
    const float* b2    = (const float*)d_in[6];
    const float* gamma = (const float*)d_in[7];
    const float* beta  = (const float*)d_in[8];
    float* out = (float*)d_out;

    char* ws = (char*)d_ws;
    size_t o = 0;
    auto alloc = [&](size_t bytes) {
        size_t r = o;
        o = (o + bytes + 255) & ~(size_t)255;
        return r;
    };
    size_t o_offs    = alloc((NEXP + 1) * 4);
    size_t o_topidx  = alloc((size_t)T_TOKENS * 2 * 4);
    size_t o_topw    = alloc((size_t)T_TOKENS * 2 * 4);
    size_t o_slotof  = alloc((size_t)T_TOKENS * 2 * 4);
    size_t o_bhist   = alloc((size_t)GATE_BLOCKS * NEXP * 4);
    size_t o_bbase   = alloc((size_t)GATE_BLOCKS * NEXP * 4);
    size_t o_w1t     = alloc((size_t)NEXP * DMODEL * FFN * 2);
    size_t o_w2t     = alloc((size_t)NEXP * DMODEL * FFN * 2);
    size_t o_xg      = alloc((size_t)MAXSLOTS * DMODEL * 2);
    size_t o_h       = alloc((size_t)MAXSLOTS * FFN * 2);
    size_t o_obuf    = alloc((size_t)MAXSLOTS * DMODEL * 2);
    (void)ws_size; (void)in_sizes; (void)n_in; (void)out_size;

    int*      offs     = (int*)(ws + o_offs);
    int*      top_idx  = (int*)(ws + o_topidx);
    float*    top_w    = (float*)(ws + o_topw);
    int*      slot_of  = (int*)(ws + o_slotof);
    int*      blk_hist = (int*)(ws + o_bhist);
    int*      blk_base = (int*)(ws + o_bbase);
    ushort_t* W1T      = (ushort_t*)(ws + o_w1t);
    ushort_t* W2T      = (ushort_t*)(ws + o_w2t);
    ushort_t* Xg       = (ushort_t*)(ws + o_xg);
    ushort_t* H        = (ushort_t*)(ws + o_h);
    ushort_t* Obuf     = (ushort_t*)(ws + o_obuf);

    gate_kernel<<<GATE_BLOCKS, 256, 0, stream>>>(x, Wg, bg, top_idx, top_w, blk_hist);
    transpose_kernel<<<8192, 256, 0, stream>>>(W1, W2, W1T, W2T);
    scan_kernel<<<1, 512, 0, stream>>>(blk_hist, blk_base, offs);
    scatter_gather_kernel<<<T_TOKENS, 256, 0, stream>>>(x, top_idx, offs, blk_base, slot_of, Xg);
    expert_gemm<DMODEL, FFN, true>
        <<<dim3(NEXP, FFN / 128, MAX_MT), 256, 0, stream>>>(Xg, W1T, b1, H, offs);
    expert_gemm<FFN, DMODEL, false>
        <<<dim3(NEXP, DMODEL / 128, MAX_MT), 256, 0, stream>>>(H, W2T, b2, Obuf, offs);
    ln_kernel<<<T_TOKENS, 256, 0, stream>>>(x, Obuf, slot_of, top_w, gamma, beta, out);
}